// Round 2
// baseline (168.902 us; speedup 1.0000x reference)
//
#include <hip/hip_runtime.h>
#include <math.h>

#define N_LAYERS 4
#define SEQ      34
#define BATCH_N  16384
#define NE       16        // batch elements per block (lane % 16)
#define NSLOT    8         // query slots per element (tid / 16)
#define NT       5         // max positions owned by one slot
#define VOCAB    14
// (1/sqrt(3)) * log2(e): fold attention scale AND exp->exp2 into q
#define QSCALE   0.8329806647638704f

typedef float f32x2 __attribute__((ext_vector_type(2)));

static __device__ __forceinline__ f32x2 mk2(float a, float b) {
    f32x2 r; r.x = a; r.y = b; return r;
}

__global__ __launch_bounds__(NE * NSLOT) void addtrans_kernel(
    const int*   __restrict__ idx,      // (B, 34)
    const float* __restrict__ tok_emb,  // (14, 3)
    const float* __restrict__ pos_enc,  // (34, 3)
    const float* __restrict__ ln_w,     // (4, 6)
    const float* __restrict__ ln_b,     // (4, 6)
    const float* __restrict__ q1w,      // (4, 3, 3)
    const float* __restrict__ k1w,
    const float* __restrict__ v1w,
    const float* __restrict__ q2w,
    const float* __restrict__ k2w,
    const float* __restrict__ v2w,
    const float* __restrict__ out_w,    // (4, 6, 6)
    const float* __restrict__ lnf_w,    // (6,)
    const float* __restrict__ lnf_b,    // (6,)
    const float* __restrict__ head_w,   // (14, 6)
    float* __restrict__ out)            // (B, 34, 14)
{
    // K/V for one layer, packed head1/head2 PAIRS, 3 float4 per (t, e):
    //   chunk0={k1_0,k2_0,k1_1,k2_1} chunk1={k1_2,k2_2,v1_0,v2_0}
    //   chunk2={v1_1,v2_1,v1_2,v2_2}
    // Pair layout feeds v_pk_fma_f32 (packed dual-fp32) in the j-loop.
    // layout [chunk*SEQ + t][e]; +1 row pad absorbs the j+1 prefetch overread.
    __shared__ float4 kvs[3 * SEQ + 1][NE];

    const int x = threadIdx.x & (NE - 1);      // element
    const int y = threadIdx.x >> 4;            // slot 0..7
    const int b = (int)blockIdx.x * NE + x;

    // Owned rows, ASCENDING: enables a segmented j-loop whose active-row
    // set is static per segment (no per-row conditionals in the hot loop).
    int rp[NT];
    rp[0] = y;
    rp[1] = 8 + y;
    rp[2] = 16 + y;
    rp[3] = 24 + y;
    rp[4] = (y < 2) ? (32 + y) : -1;           // -1 = absent

    // ---- embedding ----
    float xs[NT][6];
    #pragma unroll
    for (int k = 0; k < NT; ++k) {
        const int t = rp[k];
        if (t >= 0) {
            const int tok = idx[(size_t)b * SEQ + t];
            xs[k][0] = tok_emb[tok * 3 + 0];
            xs[k][1] = tok_emb[tok * 3 + 1];
            xs[k][2] = tok_emb[tok * 3 + 2];
            xs[k][3] = pos_enc[t * 3 + 0];
            xs[k][4] = pos_enc[t * 3 + 1];
            xs[k][5] = pos_enc[t * 3 + 2];
        }
    }

    // qp[k][i] = (q1_i, q2_i) * QSCALE.  Row 4 runs UNCONDITIONALLY in the
    // segmented loop for issue-balance across waves; non-owning lanes keep
    // qp[4]=0 -> p=exp2(0)=1 -> finite garbage in acc[4], never read.
    f32x2 qp[NT][3];
    #pragma unroll
    for (int i = 0; i < 3; ++i) qp[4][i] = mk2(0.f, 0.f);

    for (int l = 0; l < N_LAYERS; ++l) {
        __syncthreads();   // WAR: previous layer's attention reads complete

        // ---- phase 1: LN + packed q/k/v projections, stage K/V pairs ----
        #pragma unroll
        for (int k = 0; k < NT; ++k) {
            const int t = rp[k];
            if (t >= 0) {
                float h[6];
                {
                    const float* v = xs[k];
                    float m = (v[0]+v[1]+v[2]+v[3]+v[4]+v[5]) * (1.0f/6.0f);
                    float var = 0.f;
                    #pragma unroll
                    for (int i = 0; i < 6; ++i) { float d = v[i]-m; var += d*d; }
                    var *= (1.0f/6.0f);
                    float r = rsqrtf(var + 1e-5f);
                    #pragma unroll
                    for (int i = 0; i < 6; ++i)
                        h[i] = (v[i]-m) * r * ln_w[l*6+i] + ln_b[l*6+i];
                }
                // hp_j = (h_j, h_{3+j}): head1 uses h[0:3], head2 h[3:6]
                f32x2 hp0 = mk2(h[0], h[3]);
                f32x2 hp1 = mk2(h[1], h[4]);
                f32x2 hp2 = mk2(h[2], h[5]);
                f32x2 kkp[3], vvp[3];
                #pragma unroll
                for (int i = 0; i < 3; ++i) {
                    const int w = l*9 + i*3;
                    f32x2 q = mk2(q1w[w  ], q2w[w  ]) * hp0
                            + mk2(q1w[w+1], q2w[w+1]) * hp1
                            + mk2(q1w[w+2], q2w[w+2]) * hp2;
                    qp[k][i] = q * QSCALE;
                    kkp[i]   = mk2(k1w[w  ], k2w[w  ]) * hp0
                             + mk2(k1w[w+1], k2w[w+1]) * hp1
                             + mk2(k1w[w+2], k2w[w+2]) * hp2;
                    vvp[i]   = mk2(v1w[w  ], v2w[w  ]) * hp0
                             + mk2(v1w[w+1], v2w[w+1]) * hp1
                             + mk2(v1w[w+2], v2w[w+2]) * hp2;
                }
                kvs[0*SEQ + t][x] = make_float4(kkp[0].x, kkp[0].y, kkp[1].x, kkp[1].y);
                kvs[1*SEQ + t][x] = make_float4(kkp[2].x, kkp[2].y, vvp[0].x, vvp[0].y);
                kvs[2*SEQ + t][x] = make_float4(vvp[1].x, vvp[1].y, vvp[2].x, vvp[2].y);
            }
        }
        __syncthreads();   // RAW: K/V visible

        // ---- phase 2: segmented causal attention, fully branchless ----
        // single-pass softmax (no max subtract: |s*log2e| < 46, fp32-safe)
        f32x2 ls[NT], acc[NT][3];
        #pragma unroll
        for (int k = 0; k < NT; ++k) {
            ls[k] = mk2(0.f, 0.f);
            acc[k][0] = acc[k][1] = acc[k][2] = mk2(0.f, 0.f);
        }

        float4 c0 = kvs[0][x], c1 = kvs[SEQ][x], c2 = kvs[2*SEQ][x];
        int j = 0;

        #define LOADN \
            float4 n0 = kvs[j + 1][x]; \
            float4 n1 = kvs[SEQ + j + 1][x]; \
            float4 n2 = kvs[2*SEQ + j + 1][x]; \
            f32x2 kp0 = mk2(c0.x, c0.y), kp1 = mk2(c0.z, c0.w), kp2 = mk2(c1.x, c1.y); \
            f32x2 vp0 = mk2(c1.z, c1.w), vp1 = mk2(c2.x, c2.y), vp2 = mk2(c2.z, c2.w);
        #define ROWM(k) { \
            f32x2 s = qp[k][0]*kp0 + qp[k][1]*kp1 + qp[k][2]*kp2; \
            f32x2 p = mk2(__builtin_amdgcn_exp2f(s.x), __builtin_amdgcn_exp2f(s.y)); \
            ls[k] += p; \
            acc[k][0] += p*vp0; acc[k][1] += p*vp1; acc[k][2] += p*vp2; }
        #define ROLL c0 = n0; c1 = n1; c2 = n2;

        // seg0: j in [0, y] — rows 0..4 (trip 1..8, mildly divergent)
        for (; j <= rp[0]; ++j) { LOADN ROWM(0) ROWM(1) ROWM(2) ROWM(3) ROWM(4) ROLL }
        // seg1: 8 iters, uniform for every lane — rows 1..4
        #pragma unroll
        for (int it = 0; it < 8; ++it, ++j) { LOADN ROWM(1) ROWM(2) ROWM(3) ROWM(4) ROLL }
        // seg2: 8 iters — rows 2..4
        #pragma unroll
        for (int it = 0; it < 8; ++it, ++j) { LOADN ROWM(2) ROWM(3) ROWM(4) ROLL }
        // seg3: 8 iters — rows 3..4
        #pragma unroll
        for (int it = 0; it < 8; ++it, ++j) { LOADN ROWM(3) ROWM(4) ROLL }
        // seg4: row 4 tail (only y<2 lanes; empty + cheap exit elsewhere)
        for (; j <= rp[4]; ++j) { LOADN ROWM(4) ROLL }

        #undef LOADN
        #undef ROWM
        #undef ROLL

        // ---- epilogue: normalize, packed output projection + residual ----
        #pragma unroll
        for (int k = 0; k < NT; ++k) {
            if (rp[k] >= 0) {
                const f32x2 inv = mk2(__builtin_amdgcn_rcpf(ls[k].x),
                                      __builtin_amdgcn_rcpf(ls[k].y));
                // op_j = (o_j, o_{3+j})
                f32x2 op0 = acc[k][0] * inv;
                f32x2 op1 = acc[k][1] * inv;
                f32x2 op2 = acc[k][2] * inv;
                #pragma unroll
                for (int i = 0; i < 6; ++i) {
                    const int w = l*36 + i*6;
                    f32x2 t2 = mk2(out_w[w+0], out_w[w+3]) * op0
                             + mk2(out_w[w+1], out_w[w+4]) * op1
                             + mk2(out_w[w+2], out_w[w+5]) * op2;
                    xs[k][i] += t2.x + t2.y;
                }
            }
        }
    }

    // ---- final layernorm + head ----
    #pragma unroll
    for (int k = 0; k < NT; ++k) {
        const int t = rp[k];
        if (t >= 0) {
            float hf[6];
            {
                const float* v = xs[k];
                float m = (v[0]+v[1]+v[2]+v[3]+v[4]+v[5]) * (1.0f/6.0f);
                float var = 0.f;
                #pragma unroll
                for (int i = 0; i < 6; ++i) { float d = v[i]-m; var += d*d; }
                var *= (1.0f/6.0f);
                float r = rsqrtf(var + 1e-5f);
                #pragma unroll
                for (int i = 0; i < 6; ++i)
                    hf[i] = (v[i]-m) * r * lnf_w[i] + lnf_b[i];
            }
            float lg[VOCAB];
            #pragma unroll
            for (int c = 0; c < VOCAB; ++c) {
                const int w = c*6;
                lg[c] = head_w[w+0]*hf[0] + head_w[w+1]*hf[1] + head_w[w+2]*hf[2]
                      + head_w[w+3]*hf[3] + head_w[w+4]*hf[4] + head_w[w+5]*hf[5];
            }
            float2* op = (float2*)(out + ((size_t)b * SEQ + t) * VOCAB);
            #pragma unroll
            for (int c = 0; c < 7; ++c)
                op[c] = make_float2(lg[2*c], lg[2*c+1]);
        }
    }
}

extern "C" void kernel_launch(void* const* d_in, const int* in_sizes, int n_in,
                              void* d_out, int out_size, void* d_ws, size_t ws_size,
                              hipStream_t stream) {
    const int*   idx     = (const int*)  d_in[0];
    const float* tok_emb = (const float*)d_in[1];
    const float* pos_enc = (const float*)d_in[2];
    const float* ln_w    = (const float*)d_in[3];
    const float* ln_b    = (const float*)d_in[4];
    const float* q1w     = (const float*)d_in[5];
    const float* k1w     = (const float*)d_in[6];
    const float* v1w     = (const float*)d_in[7];
    const float* q2w     = (const float*)d_in[8];
    const float* k2w     = (const float*)d_in[9];
    const float* v2w     = (const float*)d_in[10];
    const float* out_w   = (const float*)d_in[11];
    const float* lnf_w   = (const float*)d_in[12];
    const float* lnf_b   = (const float*)d_in[13];
    const float* head_w  = (const float*)d_in[14];
    float* out = (float*)d_out;

    const int grid = BATCH_N / NE;   // 1024 blocks of 128 threads
    addtrans_kernel<<<grid, NE * NSLOT, 0, stream>>>(
        idx, tok_emb, pos_enc, ln_w, ln_b,
        q1w, k1w, v1w, q2w, k2w, v2w,
        out_w, lnf_w, lnf_b, head_w, out);
}

// Round 3
// 139.353 us; speedup vs baseline: 1.2120x; 1.2120x over previous
//
#include <hip/hip_runtime.h>
#include <math.h>

#define N_LAYERS 4
#define SEQ      34
#define BATCH_N  16384
#define NE       16        // batch elements per block (lane % 16)
#define NSLOT    8         // query slots per element (lane / 16)
#define NT       5         // max positions owned by one slot
#define VOCAB    14
// (1/sqrt(3)) * log2(e): fold attention scale AND exp->exp2 into q
#define QSCALE   0.8329806647638704f

typedef float f32x2 __attribute__((ext_vector_type(2)));

static __device__ __forceinline__ f32x2 mk2(float a, float b) {
    f32x2 r; r.x = a; r.y = b; return r;
}

__global__ __launch_bounds__(128) void addtrans_kernel(
    const int*   __restrict__ idx,      // (B, 34)
    const float* __restrict__ tok_emb,  // (14, 3)
    const float* __restrict__ pos_enc,  // (34, 3)
    const float* __restrict__ ln_w,     // (4, 6)
    const float* __restrict__ ln_b,     // (4, 6)
    const float* __restrict__ q1w,      // (4, 3, 3)
    const float* __restrict__ k1w,
    const float* __restrict__ v1w,
    const float* __restrict__ q2w,
    const float* __restrict__ k2w,
    const float* __restrict__ v2w,
    const float* __restrict__ out_w,    // (4, 6, 6)
    const float* __restrict__ lnf_w,    // (6,)
    const float* __restrict__ lnf_b,    // (6,)
    const float* __restrict__ head_w,   // (14, 6)
    float* __restrict__ out)            // (B, 34, 14)
{
    // K/V for one layer, packed as (head1_i, head2_i) PAIRS, 3 float4/(t,e):
    //   chunk0={k1_0,k2_0,k1_1,k2_1} chunk1={k1_2,k2_2,v1_0,v2_0}
    //   chunk2={v1_1,v2_1,v1_2,v2_2}
    // Pair components sit in consecutive VGPRs after ds_read_b128, feeding
    // v_pk_fma_f32 with zero repack cost.
    // layout [chunk*SEQ + t][e]; +1 row pad absorbs the j+1 prefetch overread.
    __shared__ float4 kvs[3 * SEQ + 1][NE];

    const int x = threadIdx.x & (NE - 1);      // element
    const int y = threadIdx.x >> 4;            // slot 0..7
    const int b = (int)blockIdx.x * NE + x;

    // slot y owns t = {jmax, y, 8+y, 16+y, 24+y?}; one merged j-loop to jmax
    // serves all of them (each LDS read amortized over 4-5 query rows).
    int tp[NT];
    tp[0] = (y < 2) ? (32 + y) : (24 + y);     // the longest row first (unconditional)
    tp[1] = y;
    tp[2] = 8 + y;
    tp[3] = 16 + y;
    tp[4] = (y < 2) ? (24 + y) : -1;           // -1 = absent
    const int jmax = tp[0];

    // ---- embedding ----
    float xs[NT][6];
    #pragma unroll
    for (int k = 0; k < NT; ++k) {
        const int t = tp[k];
        if (t >= 0) {
            const int tok = idx[(size_t)b * SEQ + t];
            xs[k][0] = tok_emb[tok * 3 + 0];
            xs[k][1] = tok_emb[tok * 3 + 1];
            xs[k][2] = tok_emb[tok * 3 + 2];
            xs[k][3] = pos_enc[t * 3 + 0];
            xs[k][4] = pos_enc[t * 3 + 1];
            xs[k][5] = pos_enc[t * 3 + 2];
        }
    }

    // qp[k][i] = (q1_i, q2_i) * QSCALE, a register pair for v_pk_fma_f32
    f32x2 qp[NT][3];

    for (int l = 0; l < N_LAYERS; ++l) {
        __syncthreads();   // WAR: previous layer's attention reads complete

        // ---- phase 1: LN + q/k/v projections for each owned t, stage K/V ----
        // (scalar, as R0 — weights are SGPR-uniform, folding into v_fma free)
        #pragma unroll
        for (int k = 0; k < NT; ++k) {
            const int t = tp[k];
            if (t >= 0) {
                float h[6];
                {
                    const float* v = xs[k];
                    float m = (v[0]+v[1]+v[2]+v[3]+v[4]+v[5]) * (1.0f/6.0f);
                    float var = 0.f;
                    #pragma unroll
                    for (int i = 0; i < 6; ++i) { float d = v[i]-m; var += d*d; }
                    var *= (1.0f/6.0f);
                    float r = rsqrtf(var + 1e-5f);
                    #pragma unroll
                    for (int i = 0; i < 6; ++i)
                        h[i] = (v[i]-m) * r * ln_w[l*6+i] + ln_b[l*6+i];
                }
                float kk[6], vv[6];
                #pragma unroll
                for (int i = 0; i < 3; ++i) {
                    const int w = l*9 + i*3;
                    float q1 = (q1w[w]*h[0] + q1w[w+1]*h[1] + q1w[w+2]*h[2]) * QSCALE;
                    float q2 = (q2w[w]*h[3] + q2w[w+1]*h[4] + q2w[w+2]*h[5]) * QSCALE;
                    qp[k][i] = mk2(q1, q2);
                    kk[i]    =  k1w[w]*h[0] + k1w[w+1]*h[1] + k1w[w+2]*h[2];
                    vv[i]    =  v1w[w]*h[0] + v1w[w+1]*h[1] + v1w[w+2]*h[2];
                    kk[3+i]  =  k2w[w]*h[3] + k2w[w+1]*h[4] + k2w[w+2]*h[5];
                    vv[3+i]  =  v2w[w]*h[3] + v2w[w+1]*h[4] + v2w[w+2]*h[5];
                }
                // interleaved (head1_i, head2_i) pair layout
                kvs[0*SEQ + t][x] = make_float4(kk[0], kk[3], kk[1], kk[4]);
                kvs[1*SEQ + t][x] = make_float4(kk[2], kk[5], vv[0], vv[3]);
                kvs[2*SEQ + t][x] = make_float4(vv[1], vv[4], vv[2], vv[5]);
            }
        }
        __syncthreads();   // RAW: K/V visible

        // ---- phase 2: merged causal attention over all owned t's ----
        // single-pass softmax (no max subtract: |s*log2e| < 46, fp32-safe)
        // packed dual-fp32: both heads per v_pk_* instruction
        f32x2 ls[NT], acc[NT][3];
        #pragma unroll
        for (int k = 0; k < NT; ++k) {
            ls[k] = mk2(0.f, 0.f);
            acc[k][0] = acc[k][1] = acc[k][2] = mk2(0.f, 0.f);
        }
        float4 c0 = kvs[0][x], c1 = kvs[SEQ][x], c2 = kvs[2*SEQ][x];
        #pragma unroll 2
        for (int j = 0; j <= jmax; ++j) {
            float4 n0 = kvs[j + 1][x];
            float4 n1 = kvs[SEQ + j + 1][x];
            float4 n2 = kvs[2*SEQ + j + 1][x];
            f32x2 kp0 = mk2(c0.x, c0.y), kp1 = mk2(c0.z, c0.w), kp2 = mk2(c1.x, c1.y);
            f32x2 vp0 = mk2(c1.z, c1.w), vp1 = mk2(c2.x, c2.y), vp2 = mk2(c2.z, c2.w);
            #pragma unroll
            for (int k = 0; k < NT; ++k) {
                if (k == 0 || j <= tp[k]) {   // k=0 unconditional; tp=-1 never fires
                    f32x2 s = qp[k][0]*kp0 + qp[k][1]*kp1 + qp[k][2]*kp2;
                    f32x2 p = mk2(__builtin_amdgcn_exp2f(s.x),
                                  __builtin_amdgcn_exp2f(s.y));
                    ls[k] += p;
                    acc[k][0] += p*vp0; acc[k][1] += p*vp1; acc[k][2] += p*vp2;
                }
            }
            c0 = n0; c1 = n1; c2 = n2;
        }

        // ---- epilogue: normalize, output projection + residual (scalar) ----
        #pragma unroll
        for (int k = 0; k < NT; ++k) {
            if (tp[k] >= 0) {
                const float i1 = __builtin_amdgcn_rcpf(ls[k].x);
                const float i2 = __builtin_amdgcn_rcpf(ls[k].y);
                float o[6] = { acc[k][0].x*i1, acc[k][1].x*i1, acc[k][2].x*i1,
                               acc[k][0].y*i2, acc[k][1].y*i2, acc[k][2].y*i2 };
                #pragma unroll
                for (int i = 0; i < 6; ++i) {
                    const int w = l*36 + i*6;
                    xs[k][i] += out_w[w+0]*o[0] + out_w[w+1]*o[1] + out_w[w+2]*o[2]
                              + out_w[w+3]*o[3] + out_w[w+4]*o[4] + out_w[w+5]*o[5];
                }
            }
        }
    }

    // ---- final layernorm + head ----
    #pragma unroll
    for (int k = 0; k < NT; ++k) {
        const int t = tp[k];
        if (t >= 0) {
            float hf[6];
            {
                const float* v = xs[k];
                float m = (v[0]+v[1]+v[2]+v[3]+v[4]+v[5]) * (1.0f/6.0f);
                float var = 0.f;
                #pragma unroll
                for (int i = 0; i < 6; ++i) { float d = v[i]-m; var += d*d; }
                var *= (1.0f/6.0f);
                float r = rsqrtf(var + 1e-5f);
                #pragma unroll
                for (int i = 0; i < 6; ++i)
                    hf[i] = (v[i]-m) * r * lnf_w[i] + lnf_b[i];
            }
            float lg[VOCAB];
            #pragma unroll
            for (int c = 0; c < VOCAB; ++c) {
                const int w = c*6;
                lg[c] = head_w[w+0]*hf[0] + head_w[w+1]*hf[1] + head_w[w+2]*hf[2]
                      + head_w[w+3]*hf[3] + head_w[w+4]*hf[4] + head_w[w+5]*hf[5];
            }
            float2* op = (float2*)(out + ((size_t)b * SEQ + t) * VOCAB);
            #pragma unroll
            for (int c = 0; c < 7; ++c)
                op[c] = make_float2(lg[2*c], lg[2*c+1]);
        }
    }
}

extern "C" void kernel_launch(void* const* d_in, const int* in_sizes, int n_in,
                              void* d_out, int out_size, void* d_ws, size_t ws_size,
                              hipStream_t stream) {
    const int*   idx     = (const int*)  d_in[0];
    const float* tok_emb = (const float*)d_in[1];
    const float* pos_enc = (const float*)d_in[2];
    const float* ln_w    = (const float*)d_in[3];
    const float* ln_b    = (const float*)d_in[4];
    const float* q1w     = (const float*)d_in[5];
    const float* k1w     = (const float*)d_in[6];
    const float* v1w     = (const float*)d_in[7];
    const float* q2w     = (const float*)d_in[8];
    const float* k2w     = (const float*)d_in[9];
    const float* v2w     = (const float*)d_in[10];
    const float* out_w   = (const float*)d_in[11];
    const float* lnf_w   = (const float*)d_in[12];
    const float* lnf_b   = (const float*)d_in[13];
    const float* head_w  = (const float*)d_in[14];
    float* out = (float*)d_out;

    const int grid = BATCH_N / NE;   // 1024 blocks of 128 threads
    addtrans_kernel<<<grid, NE * NSLOT, 0, stream>>>(
        idx, tok_emb, pos_enc, ln_w, ln_b,
        q1w, k1w, v1w, q2w, k2w, v2w,
        out_w, lnf_w, lnf_b, head_w, out);
}